// Round 5
// baseline (542.094 us; speedup 1.0000x reference)
//
#include <hip/hip_runtime.h>

constexpr int NL    = 48;
constexpr int SEQ   = 1024;
constexpr int BATCH = 512;

typedef float f32x2 __attribute__((ext_vector_type(2)));

__device__ __forceinline__ float bperm(int byte_addr, int src_i) {
    return __int_as_float(__builtin_amdgcn_ds_bpermute(byte_addr, src_i));
}

// One step of the linear-domain forward recurrence (bpermute-broadcast).
// Broadcast all 48 v-values via ds_bpermute (uniform index -> lane-i pull):
// VGPR destinations on the LDS pipe, no SGPR-write hazards (round 4's 387
// cy/step stall was the v_readlane->SGPR->VALU wait-state hazard, 48x8 cy).
// FMAs paired as ext_vector float2 to invite v_pk_fma_f32. RN_: renorm max
// over the same broadcast values via a depth-5 max tree (parallel to the
// FMA chain); scale folds into this step's output on both mask paths.
#define CRF_STEP(T_, SLOT_, RN_) do {                                         \
    float ee_ = __expf(embuf[SLOT_]);                                         \
    int   mt_ = mbuf[SLOT_];                                                  \
    int   tn_ = (T_) + 8; if (tn_ > SEQ - 1) tn_ = SEQ - 1;                   \
    embuf[SLOT_] = em[tn_ * NL + jc];                                         \
    mbuf[SLOT_]  = mk[tn_];                                                   \
    const int vi_ = __float_as_int(v);                                        \
    f32x2 bv_[24];                                                            \
    _Pragma("unroll")                                                         \
    for (int p_ = 0; p_ < 24; ++p_) {                                         \
        bv_[p_].x = bperm(bp0 + 8 * p_,     vi_);                             \
        bv_[p_].y = bperm(bp0 + 8 * p_ + 4, vi_);                             \
    }                                                                         \
    float rm_ = 1.0f;                                                         \
    if (RN_) {                                                                \
        f32x2 m12_[12];                                                       \
        _Pragma("unroll")                                                     \
        for (int k_ = 0; k_ < 12; ++k_)                                       \
            m12_[k_] = __builtin_elementwise_max(bv_[k_], bv_[k_ + 12]);      \
        f32x2 m6_[6];                                                         \
        _Pragma("unroll")                                                     \
        for (int k_ = 0; k_ < 6; ++k_)                                        \
            m6_[k_] = __builtin_elementwise_max(m12_[k_], m12_[k_ + 6]);      \
        f32x2 m3a_ = __builtin_elementwise_max(m6_[0], m6_[3]);               \
        f32x2 m3b_ = __builtin_elementwise_max(m6_[1], m6_[4]);               \
        f32x2 m3c_ = __builtin_elementwise_max(m6_[2], m6_[5]);               \
        f32x2 mm_  = __builtin_elementwise_max(m3a_,                          \
                       __builtin_elementwise_max(m3b_, m3c_));                \
        float m_ = fmaxf(mm_.x, mm_.y);                                       \
        rm_ = __builtin_amdgcn_rcpf(m_);                                      \
        S += __logf(m_);                                                      \
    }                                                                         \
    f32x2 c0_ = {0.f, 0.f}, c1_ = {0.f, 0.f};                                 \
    f32x2 c2_ = {0.f, 0.f}, c3_ = {0.f, 0.f};                                 \
    _Pragma("unroll")                                                         \
    for (int p_ = 0; p_ < 24; p_ += 4) {                                      \
        c0_ += bv_[p_ + 0] * Ec2[p_ + 0];                                     \
        c1_ += bv_[p_ + 1] * Ec2[p_ + 1];                                     \
        c2_ += bv_[p_ + 2] * Ec2[p_ + 2];                                     \
        c3_ += bv_[p_ + 3] * Ec2[p_ + 3];                                     \
    }                                                                         \
    f32x2 d0_ = c0_ + c1_, d1_ = c2_ + c3_;                                   \
    f32x2 d_  = d0_ + d1_;                                                    \
    float acc_ = d_.x + d_.y;                                                 \
    v = (mt_ ? acc_ * ee_ : v) * rm_;                                         \
} while (0)

// Block = 128: wave 0 = forward recurrence, wave 1 = gold score.
// amdgpu_waves_per_eu(1,1): full VGPR budget so Ec2[24]/bv_[24]/ring stay
// in architectural VGPRs (132 VGPRs at round 4; was 60 before).
__global__ __launch_bounds__(128)
__attribute__((amdgpu_waves_per_eu(1, 1)))
void crf_fused(
    const float* __restrict__ emissions, const int* __restrict__ labels,
    const int* __restrict__ mask, const float* __restrict__ trans,
    const float* __restrict__ startt, const float* __restrict__ endt,
    float* __restrict__ gold_out, float* __restrict__ fwd_out)
{
    const int b   = blockIdx.x;
    const int tid = threadIdx.x;
    const float* em = emissions + (size_t)b * SEQ * NL;
    const int*   mk = mask + b * SEQ;

    if (tid < 64) {
        // ---------------- wave 0: forward algorithm ----------------
        const int  j   = tid;                  // lanes 48..63 mirror lane 47
        const bool act = (j < NL);
        const int  jc  = act ? j : NL - 1;

        // Runtime zero (grid is 1-D so blockIdx.y==0) the compiler can't
        // constant-fold: keeps ONE shared ds_bpermute address VGPR, with
        // each 4*i folded into the DS offset immediate (no per-step movs).
        const int bp0 = (int)blockIdx.y * 4;

        // E column jc as float2 row-pairs: Ec2[p] = (e^T[2p][jc], e^T[2p+1][jc]).
        f32x2 Ec2[24];
        #pragma unroll
        for (int p = 0; p < 24; ++p) {
            Ec2[p].x = __expf(trans[(2 * p)     * NL + jc]);
            Ec2[p].y = __expf(trans[(2 * p + 1) * NL + jc]);
        }

        // init: score0 = start + emit[0]; normalize by wave max.
        float s0 = act ? (startt[jc] + em[jc]) : -3.0e38f;
        float m0 = s0;
        #pragma unroll
        for (int o = 32; o; o >>= 1) m0 = fmaxf(m0, __shfl_xor(m0, o));
        float v = act ? __expf(s0 - m0) : 0.0f;
        float S = m0;

        // 8-deep prefetch ring for emissions + mask.
        float embuf[8]; int mbuf[8];
        #pragma unroll
        for (int t = 1; t <= 8; ++t) { embuf[t & 7] = em[t * NL + jc]; mbuf[t & 7] = mk[t]; }

        // peeled steps 1..7; renorm at step 5 (max over v from step 4).
        CRF_STEP(1, 1, 0); CRF_STEP(2, 2, 0); CRF_STEP(3, 3, 0); CRF_STEP(4, 4, 0);
        CRF_STEP(5, 5, 1); CRF_STEP(6, 6, 0); CRF_STEP(7, 7, 0);

        // aligned chunks of 8: tb = 8,16,...,1016 covers t = 8..1023.
        // renorm at tb+0 and tb+4 -> every <=4 steps (fp32-safe growth).
        for (int tb = 8; tb <= SEQ - 8; tb += 8) {
            CRF_STEP(tb + 0, 0, 1);
            CRF_STEP(tb + 1, 1, 0); CRF_STEP(tb + 2, 2, 0); CRF_STEP(tb + 3, 3, 0);
            CRF_STEP(tb + 4, 4, 1);
            CRF_STEP(tb + 5, 5, 0); CRF_STEP(tb + 6, 6, 0); CRF_STEP(tb + 7, 7, 0);
        }

        // fwd = S + log(sum_j v[j] * exp(end[j])) over active lanes.
        float w = act ? v * __expf(endt[jc]) : 0.0f;
        #pragma unroll
        for (int o = 32; o; o >>= 1) w += __shfl_xor(w, o);
        if (j == 0) fwd_out[b] = S + __logf(w);
    } else {
        // ---------------- wave 1: gold score ----------------
        const int l = tid - 64;
        const int* lb = labels + b * SEQ;

        float part = 0.0f; int mcnt = 0;
        for (int t = l; t < SEQ; t += 64) {
            int lt = lb[t];
            int mt = mk[t];
            mcnt += mt;
            if (t == 0) {
                part += startt[lt] + em[lt];
            } else {
                float e  = em[t * NL + lt];
                float tr = trans[lt * NL + lb[t - 1]];   // gold uses T[cur][prev]
                if (mt) part += e + tr;
            }
        }
        #pragma unroll
        for (int o = 32; o; o >>= 1) {
            part += __shfl_xor(part, o);
            mcnt += __shfl_xor(mcnt, o);
        }
        if (l == 0) {
            int len = mcnt - 1;
            gold_out[b] = part + endt[lb[len]];
        }
    }
}

__global__ __launch_bounds__(64) void crf_reduce(
    const float* __restrict__ gold, const float* __restrict__ fwd,
    float* __restrict__ out)
{
    const int l = threadIdx.x;
    float s = 0.0f;
    for (int bIdx = l; bIdx < BATCH; bIdx += 64) s += fwd[bIdx] - gold[bIdx];
    #pragma unroll
    for (int o = 32; o; o >>= 1) s += __shfl_xor(s, o);
    if (l == 0) out[0] = s * (1.0f / (float)BATCH);
}

extern "C" void kernel_launch(void* const* d_in, const int* in_sizes, int n_in,
                              void* d_out, int out_size, void* d_ws, size_t ws_size,
                              hipStream_t stream) {
    const float* emissions = (const float*)d_in[0];
    const int*   labels    = (const int*)d_in[1];
    const int*   mask      = (const int*)d_in[2];
    const float* trans     = (const float*)d_in[3];
    const float* startt    = (const float*)d_in[4];
    const float* endt      = (const float*)d_in[5];
    float*       out       = (float*)d_out;
    float*       wsf       = (float*)d_ws;   // [0..512) gold, [512..1024) fwd

    crf_fused<<<BATCH, 128, 0, stream>>>(emissions, labels, mask, trans, startt, endt,
                                         wsf, wsf + BATCH);
    crf_reduce<<<1, 64, 0, stream>>>(wsf, wsf + BATCH, out);
}

// Round 6
// 412.265 us; speedup vs baseline: 1.3149x; 1.3149x over previous
//
#include <hip/hip_runtime.h>

constexpr int NL    = 48;
constexpr int SEQ   = 1024;
constexpr int BATCH = 512;

// One step of the linear-domain forward recurrence, bf16-pair broadcast.
// Lane j owns column j. Pack (v[2p], v[2p+1]) as bf16x2 in one 32-bit word
// (DPP quad_perm swap + bit ops, all full-rate VALU), broadcast 24 words via
// v_readlane (half of round 4's 48), then unpack on the SCALAR pipe
// (s_lshl/s_and on the uniform SGPR) feeding v_fma as SGPR constants.
// RN_: renorm max computed with scalar-pipe unsigned maxes over the same
// packed words (positive-float bits order as unsigned; hi halves via raw
// word compare, lo halves via <<16). Scale rm_ and S += log(m) use the SAME
// m on both mask paths -> exact identity, off the critical path.
#define CRF_STEP(T_, SLOT_, RN_) do {                                         \
    float ee_ = __expf(embuf[SLOT_]);                                         \
    int   mt_ = mbuf[SLOT_];                                                  \
    int   tn_ = (T_) + 8; if (tn_ > SEQ - 1) tn_ = SEQ - 1;                   \
    embuf[SLOT_] = em[tn_ * NL + jc];                                         \
    mbuf[SLOT_]  = mk[tn_];                                                   \
    int ar_ = __float_as_int(v) + 0x8000;      /* round-to-nearest bf16 */    \
    int br_ = __builtin_amdgcn_update_dpp(0, ar_, 0xB1, 0xF, 0xF, false);     \
    int xl_ = odd ? br_ : ar_;                 /* even lane's value -> lo */  \
    int xh_ = odd ? ar_ : br_;                 /* odd lane's value  -> hi */  \
    int pk_ = (int)(((unsigned)xl_ >> 16) | ((unsigned)xh_ & 0xFFFF0000u));   \
    int sp_[24];                                                              \
    _Pragma("unroll")                                                         \
    for (int p_ = 0; p_ < 24; ++p_)                                           \
        sp_[p_] = __builtin_amdgcn_readlane(pk_, 2 * p_);                     \
    float rm_ = 1.0f;                                                         \
    if (RN_) {                                                                \
        unsigned mh_ = 0u, ml_ = 0u;                                          \
        _Pragma("unroll")                                                     \
        for (int p_ = 0; p_ < 24; ++p_) {                                     \
            unsigned u_ = (unsigned)sp_[p_];                                  \
            mh_ = (mh_ > u_) ? mh_ : u_;                                      \
            unsigned l_ = u_ << 16;                                           \
            ml_ = (ml_ > l_) ? ml_ : l_;                                      \
        }                                                                     \
        mh_ &= 0xFFFF0000u;                                                   \
        unsigned mb_ = (mh_ > ml_) ? mh_ : ml_;                               \
        float m_ = __uint_as_float(mb_);                                      \
        rm_ = __builtin_amdgcn_rcpf(m_);                                      \
        S += __logf(m_);                                                      \
    }                                                                         \
    float a0_ = 0.f, a1_ = 0.f, a2_ = 0.f, a3_ = 0.f;                         \
    _Pragma("unroll")                                                         \
    for (int p_ = 0; p_ < 24; p_ += 2) {                                      \
        float l0_ = __int_as_float((int)((unsigned)sp_[p_]     << 16));       \
        float h0_ = __int_as_float((int)((unsigned)sp_[p_]     & 0xFFFF0000u));\
        float l1_ = __int_as_float((int)((unsigned)sp_[p_ + 1] << 16));       \
        float h1_ = __int_as_float((int)((unsigned)sp_[p_ + 1] & 0xFFFF0000u));\
        a0_ = fmaf(l0_, Ec[2 * p_ + 0], a0_);                                 \
        a1_ = fmaf(h0_, Ec[2 * p_ + 1], a1_);                                 \
        a2_ = fmaf(l1_, Ec[2 * p_ + 2], a2_);                                 \
        a3_ = fmaf(h1_, Ec[2 * p_ + 3], a3_);                                 \
    }                                                                         \
    float acc_ = (a0_ + a1_) + (a2_ + a3_);                                   \
    v = (mt_ ? acc_ * ee_ : v) * rm_;                                         \
} while (0)

// Block = 128: wave 0 = forward recurrence, wave 1 = gold score.
// amdgpu_waves_per_eu(1,1): full VGPR budget keeps Ec[48] + ring in
// architectural VGPRs (proven round 4: 132 VGPRs, no AGPR shuffling).
__global__ __launch_bounds__(128)
__attribute__((amdgpu_waves_per_eu(1, 1)))
void crf_fused(
    const float* __restrict__ emissions, const int* __restrict__ labels,
    const int* __restrict__ mask, const float* __restrict__ trans,
    const float* __restrict__ startt, const float* __restrict__ endt,
    float* __restrict__ gold_out, float* __restrict__ fwd_out)
{
    const int b   = blockIdx.x;
    const int tid = threadIdx.x;
    const float* em = emissions + (size_t)b * SEQ * NL;
    const int*   mk = mask + b * SEQ;

    if (tid < 64) {
        // ---------------- wave 0: forward algorithm ----------------
        const int  j   = tid;                  // lanes 48..63 mirror lane 47
        const bool act = (j < NL);
        const int  jc  = act ? j : NL - 1;
        const bool odd = (j & 1);

        // E column jc in registers: Ec[i] = exp(T[i][jc]) (fp32, exact).
        float Ec[NL];
        #pragma unroll
        for (int i = 0; i < NL; ++i) Ec[i] = __expf(trans[i * NL + jc]);

        // init: score0 = start + emit[0]; normalize by wave max.
        float s0 = act ? (startt[jc] + em[jc]) : -3.0e38f;
        float m0 = s0;
        #pragma unroll
        for (int o = 32; o; o >>= 1) m0 = fmaxf(m0, __shfl_xor(m0, o));
        float v = act ? __expf(s0 - m0) : 0.0f;
        float S = m0;

        // 8-deep prefetch ring for emissions + mask.
        float embuf[8]; int mbuf[8];
        #pragma unroll
        for (int t = 1; t <= 8; ++t) { embuf[t & 7] = em[t * NL + jc]; mbuf[t & 7] = mk[t]; }

        // peeled steps 1..7; renorm at step 5 (max over v from step 4).
        CRF_STEP(1, 1, 0); CRF_STEP(2, 2, 0); CRF_STEP(3, 3, 0); CRF_STEP(4, 4, 0);
        CRF_STEP(5, 5, 1); CRF_STEP(6, 6, 0); CRF_STEP(7, 7, 0);

        // aligned chunks of 8: tb = 8,16,...,1016 covers t = 8..1023.
        // renorm at tb+0 and tb+4 -> every <=4 steps (growth <= ~2^76, safe).
        for (int tb = 8; tb <= SEQ - 8; tb += 8) {
            CRF_STEP(tb + 0, 0, 1);
            CRF_STEP(tb + 1, 1, 0); CRF_STEP(tb + 2, 2, 0); CRF_STEP(tb + 3, 3, 0);
            CRF_STEP(tb + 4, 4, 1);
            CRF_STEP(tb + 5, 5, 0); CRF_STEP(tb + 6, 6, 0); CRF_STEP(tb + 7, 7, 0);
        }

        // fwd = S + log(sum_j v[j] * exp(end[j])) over active lanes.
        float w = act ? v * __expf(endt[jc]) : 0.0f;
        #pragma unroll
        for (int o = 32; o; o >>= 1) w += __shfl_xor(w, o);
        if (j == 0) fwd_out[b] = S + __logf(w);
    } else {
        // ---------------- wave 1: gold score ----------------
        const int l = tid - 64;
        const int* lb = labels + b * SEQ;

        float part = 0.0f; int mcnt = 0;
        for (int t = l; t < SEQ; t += 64) {
            int lt = lb[t];
            int mt = mk[t];
            mcnt += mt;
            if (t == 0) {
                part += startt[lt] + em[lt];
            } else {
                float e  = em[t * NL + lt];
                float tr = trans[lt * NL + lb[t - 1]];   // gold uses T[cur][prev]
                if (mt) part += e + tr;
            }
        }
        #pragma unroll
        for (int o = 32; o; o >>= 1) {
            part += __shfl_xor(part, o);
            mcnt += __shfl_xor(mcnt, o);
        }
        if (l == 0) {
            int len = mcnt - 1;
            gold_out[b] = part + endt[lb[len]];
        }
    }
}

__global__ __launch_bounds__(64) void crf_reduce(
    const float* __restrict__ gold, const float* __restrict__ fwd,
    float* __restrict__ out)
{
    const int l = threadIdx.x;
    float s = 0.0f;
    for (int bIdx = l; bIdx < BATCH; bIdx += 64) s += fwd[bIdx] - gold[bIdx];
    #pragma unroll
    for (int o = 32; o; o >>= 1) s += __shfl_xor(s, o);
    if (l == 0) out[0] = s * (1.0f / (float)BATCH);
}

extern "C" void kernel_launch(void* const* d_in, const int* in_sizes, int n_in,
                              void* d_out, int out_size, void* d_ws, size_t ws_size,
                              hipStream_t stream) {
    const float* emissions = (const float*)d_in[0];
    const int*   labels    = (const int*)d_in[1];
    const int*   mask      = (const int*)d_in[2];
    const float* trans     = (const float*)d_in[3];
    const float* startt    = (const float*)d_in[4];
    const float* endt      = (const float*)d_in[5];
    float*       out       = (float*)d_out;
    float*       wsf       = (float*)d_ws;   // [0..512) gold, [512..1024) fwd

    crf_fused<<<BATCH, 128, 0, stream>>>(emissions, labels, mask, trans, startt, endt,
                                         wsf, wsf + BATCH);
    crf_reduce<<<1, 64, 0, stream>>>(wsf, wsf + BATCH, out);
}